// Round 11
// baseline (244.680 us; speedup 1.0000x reference)
//
#include <hip/hip_runtime.h>
#include <hip/hip_bf16.h>

#define TOKENS 32
#define KDIM   4096
#define NDIM   11008
#define GSZ    64
#define KP     (KDIM/2)          // qweight row length in int32 (2048)
#define NGRP   (KDIM/GSZ)        // 64 groups
#define OUTK   8                 // K-splits across blocks (== 8 XCDs)
#define BLK_COLS 128             // 4 colWaves * 32 cols
#define NBLK_C (NDIM/BLK_COLS)   // 86
#define KSLICE (KDIM/OUTK)       // 512 k per block
#define GPW    (KSLICE/2/GSZ)    // 4 groups per wave (2 inner ksegs)
#define PART_ELEMS (TOKENS*NDIM) // 352256

typedef float  f32x4 __attribute__((ext_vector_type(4)));
typedef int    i32x4 __attribute__((ext_vector_type(4)));
typedef short  s16x8 __attribute__((ext_vector_type(8)));

// Main GEMM: grid = 688 blocks, 512 thr = 8 waves.
// ob = blockIdx % 8  -> one outer-kseg per XCD (round-robin dispatch): x slice,
// sc/zp rows, and partial[ob] all XCD-local; qweight slice 2.8MB fits L2.
// Wave = (colWave cw 0..3: 32 cols via 2 B-frags) x (inner kseg ks 0..1).
// Block stages its x K-slice (32 tok x 512 k) from f32, converting to bf16
// inline, into XOR-swizzled LDS (byte lin ^ ((tok&7)<<4)); a-frag reads apply
// the same xor to the full in-row offset.
// Dequant EXACT: (float)((q>>sh)&15)*s + (-z*s)  (magic-offset fails absmax).
// Inner ksegs reduced via LDS (unioned with xs); f32 partials to ws.
// EPILOGUE FUSED: per-column-group counter in ws; the 8th arriving block
// (device-scope fence + atomicAdd, G16) sums partials o=0..7 (fixed order ->
// bit-deterministic), adds bias, writes out. No separate epi launch.
__global__ __launch_bounds__(512, 2) void awq_gemm2(
    const int* __restrict__ qw, const float* __restrict__ sc,
    const float* __restrict__ zp, const float* __restrict__ xf,
    float* __restrict__ partial, int* __restrict__ cnt,
    const float* __restrict__ bias, float* __restrict__ out) {
    __shared__ unsigned short xs[TOKENS * KSLICE];   // 32 KB (reused for reduce)
    __shared__ int lastFlag;

    const int tid  = threadIdx.x;
    const int lane = tid & 63;
    const int wid  = tid >> 6;       // 0..7
    const int cw   = wid & 3;        // colWave
    const int ks   = wid >> 2;       // inner kseg 0..1
    const int ob   = blockIdx.x & 7;         // outer kseg == XCD
    const int bc   = blockIdx.x >> 3;        // col group 0..85
    const int K0   = ob * KSLICE;

    const int col  = lane & 15;
    const int kg   = lane >> 4;                      // k-subgroup 0..3
    const int n0   = bc * BLK_COLS + cw * 32 + col;  // colset-0 column
    const int sh0  = 8 * (n0 & 3);
    const int* qp0 = qw + (n0 >> 2) * KP + kg * 4;   // colset-1 = +4*KP ints

    struct GD { float s0, z0, s1, z1; i32x4 qa0, qa1, qb0, qb1; };

    auto LOADG = [&](GD& d, int gl) {
        gl = gl < GPW ? gl : GPW - 1;                // clamp prefetch overhang
        const int gg = ob * (NGRP / OUTK) + ks * GPW + gl;  // global group
        d.s0 = sc[gg * NDIM + n0];        d.z0 = zp[gg * NDIM + n0];
        d.s1 = sc[gg * NDIM + n0 + 16];   d.z1 = zp[gg * NDIM + n0 + 16];
        const int* q = qp0 + gg * 32;
        d.qa0 = *reinterpret_cast<const i32x4*>(q);
        d.qa1 = *reinterpret_cast<const i32x4*>(q + 16);
        d.qb0 = *reinterpret_cast<const i32x4*>(q + 4 * KP);
        d.qb1 = *reinterpret_cast<const i32x4*>(q + 4 * KP + 16);
    };

    // ---- q-prefetch for groups 0/1 issued BEFORE staging (in flight across it) ----
    GD gA, gB;
    LOADG(gA, 0);
    LOADG(gB, 1);

    // ---- stage x slice: f32 global -> bf16 swizzled LDS ----
#pragma unroll
    for (int it = 0; it < 4; ++it) {
        const int lin  = it * 8192 + tid * 16;       // byte offset in bf16 slice
        const int tok  = lin >> 10;
        const int kloc = (lin & 1023) >> 1;          // = lane*8
        const float* xp = xf + tok * KDIM + K0 + kloc;
        f32x4 u0 = *reinterpret_cast<const f32x4*>(xp);
        f32x4 u1 = *reinterpret_cast<const f32x4*>(xp + 4);
        s16x8 v;
#pragma unroll
        for (int e = 0; e < 4; ++e) {
            v[e]     = __builtin_bit_cast(short, __float2bfloat16(u0[e]));
            v[e + 4] = __builtin_bit_cast(short, __float2bfloat16(u1[e]));
        }
        *reinterpret_cast<s16x8*>(
            reinterpret_cast<char*>(xs) + (lin ^ ((tok & 7) << 4))) = v;
    }
    __syncthreads();

    f32x4 acc00 = {0,0,0,0}, acc01 = {0,0,0,0};      // [colset][Mtile]
    f32x4 acc10 = {0,0,0,0}, acc11 = {0,0,0,0};

    auto LDSA = [&](int tok, int c) -> s16x8 {       // a-frag from swizzled LDS
        const int inrow = ((c << 6) + (kg << 4)) ^ ((tok & 7) << 4);
        return *reinterpret_cast<const s16x8*>(
            reinterpret_cast<const char*>(xs) + (tok << 10) + inrow);
    };

    auto DQ = [&](const i32x4& q, float s, float bz) -> s16x8 {
        s16x8 wf;
#pragma unroll
        for (int dd = 0; dd < 4; ++dd) {
            const int qd = q[dd];
            float w0 = (float)((qd >> sh0) & 15) * s + bz;        // exact dequant
            float w1 = (float)((qd >> (sh0 + 4)) & 15) * s + bz;
            wf[2 * dd]     = __builtin_bit_cast(short, __float2bfloat16(w0));
            wf[2 * dd + 1] = __builtin_bit_cast(short, __float2bfloat16(w1));
        }
        return wf;
    };

    auto COMPUTE = [&](const GD& d, int gl) {
        const int c0 = ks * 8 + gl * 2;              // local K32-chunk
        s16x8 a00 = LDSA(col, c0),      a01 = LDSA(col + 16, c0);
        s16x8 a10 = LDSA(col, c0 + 1),  a11 = LDSA(col + 16, c0 + 1);
        const float bz0 = -d.z0 * d.s0, bz1 = -d.z1 * d.s1;
        s16x8 w00 = DQ(d.qa0, d.s0, bz0), w01 = DQ(d.qa1, d.s0, bz0);
        s16x8 w10 = DQ(d.qb0, d.s1, bz1), w11 = DQ(d.qb1, d.s1, bz1);
        acc00 = __builtin_amdgcn_mfma_f32_16x16x32_bf16(a00, w00, acc00, 0, 0, 0);
        acc01 = __builtin_amdgcn_mfma_f32_16x16x32_bf16(a01, w00, acc01, 0, 0, 0);
        acc10 = __builtin_amdgcn_mfma_f32_16x16x32_bf16(a00, w10, acc10, 0, 0, 0);
        acc11 = __builtin_amdgcn_mfma_f32_16x16x32_bf16(a01, w10, acc11, 0, 0, 0);
        acc00 = __builtin_amdgcn_mfma_f32_16x16x32_bf16(a10, w01, acc00, 0, 0, 0);
        acc01 = __builtin_amdgcn_mfma_f32_16x16x32_bf16(a11, w01, acc01, 0, 0, 0);
        acc10 = __builtin_amdgcn_mfma_f32_16x16x32_bf16(a10, w11, acc10, 0, 0, 0);
        acc11 = __builtin_amdgcn_mfma_f32_16x16x32_bf16(a11, w11, acc11, 0, 0, 0);
    };

#pragma unroll
    for (int gl = 0; gl < GPW; gl += 2) {
        COMPUTE(gA, gl);     LOADG(gA, gl + 2);
        COMPUTE(gB, gl + 1); LOADG(gB, gl + 3);
    }

    // ---- inner-kseg reduction through LDS (reuse xs; done reading a-frags) ----
    __syncthreads();
    float (*red)[64][17] = reinterpret_cast<float (*)[64][17]>(xs);  // 17.4KB<32KB
    if (ks == 1) {
#pragma unroll
        for (int e = 0; e < 4; ++e) {
            red[cw][lane][e]      = acc00[e];
            red[cw][lane][4 + e]  = acc01[e];
            red[cw][lane][8 + e]  = acc10[e];
            red[cw][lane][12 + e] = acc11[e];
        }
    }
    __syncthreads();
    if (ks == 0) {
#pragma unroll
        for (int e = 0; e < 4; ++e) {
            acc00[e] += red[cw][lane][e];
            acc01[e] += red[cw][lane][4 + e];
            acc10[e] += red[cw][lane][8 + e];
            acc11[e] += red[cw][lane][12 + e];
        }
        // D layout (verified m89/m91): col = lane&15, row = (lane>>4)*4 + r
        float* pb = partial + (size_t)ob * PART_ELEMS;
#pragma unroll
        for (int r = 0; r < 4; ++r) {
            const int t = kg * 4 + r;
            pb[t * NDIM + n0]             = acc00[r];
            pb[(t + 16) * NDIM + n0]      = acc01[r];
            pb[t * NDIM + n0 + 16]        = acc10[r];
            pb[(t + 16) * NDIM + n0 + 16] = acc11[r];
        }
    }

    // ---- fused epilogue: 8th arriving block for this column-group finishes ----
    __threadfence();                         // release partial writes (device scope)
    __syncthreads();
    if (tid == 0) lastFlag = (atomicAdd(&cnt[bc], 1) == OUTK - 1);
    __syncthreads();
    if (lastFlag) {
        __threadfence();                     // acquire other blocks' partials
        const int c  = bc * BLK_COLS + (tid & 127);
        const int rb = (tid >> 7) * 8;       // rows rb..rb+7
        const float bv = bias[c];
#pragma unroll
        for (int r = 0; r < 8; ++r) {
            const int row = rb + r;
            float sum = 0.f;
#pragma unroll
            for (int o = 0; o < OUTK; ++o)   // fixed order -> deterministic
                sum += partial[(size_t)o * PART_ELEMS + row * NDIM + c];
            out[row * NDIM + c] = sum + bv;
        }
    }
}

// Fallback (ws too small): round-7 kernel, f32-x path, no ws usage.
__global__ __launch_bounds__(256, 3) void awq_gemm_fb(
    const int* __restrict__ qw, const float* __restrict__ sc,
    const float* __restrict__ zp, const float* __restrict__ bias,
    const float* __restrict__ xf, float* __restrict__ out) {
    const int lane = threadIdx.x & 63;
    const int kseg = threadIdx.x >> 6;
    const int col  = lane & 15;
    const int kg   = lane >> 4;
    const int n    = blockIdx.x * 16 + col;
    const int sh0  = 8 * (n & 3);
    const int* qp  = qw + (n >> 2) * KP + kg * 4;
    const int r0 = col, r1 = col + 16;

    f32x4 acc0 = {0,0,0,0}, acc1 = {0,0,0,0};

    auto cvt8 = [](const float* p) {
        f32x4 u0 = *reinterpret_cast<const f32x4*>(p);
        f32x4 u1 = *reinterpret_cast<const f32x4*>(p + 4);
        s16x8 o;
#pragma unroll
        for (int e = 0; e < 4; ++e) {
            o[e]     = __builtin_bit_cast(short, __float2bfloat16(u0[e]));
            o[e + 4] = __builtin_bit_cast(short, __float2bfloat16(u1[e]));
        }
        return o;
    };

    const int g_lo = kseg * (NGRP / 4), g_hi = g_lo + (NGRP / 4);
#pragma unroll 2
    for (int g = g_lo; g < g_hi; ++g) {
        const float s = sc[g * NDIM + n];
        const float bz = -zp[g * NDIM + n] * s;
#pragma unroll
        for (int h = 0; h < 2; ++h) {
            const int chunk = 2 * g + h;
            i32x4 q = *reinterpret_cast<const i32x4*>(qp + chunk * 16);
            const float* p0 = xf + r0 * KDIM + chunk * 32 + kg * 8;
            const float* p1 = xf + r1 * KDIM + chunk * 32 + kg * 8;
            s16x8 a0 = cvt8(p0), a1 = cvt8(p1);
            s16x8 wf;
#pragma unroll
            for (int dd = 0; dd < 4; ++dd) {
                const int qd = q[dd];
                float w0 = (float)((qd >> sh0) & 15) * s + bz;
                float w1 = (float)((qd >> (sh0 + 4)) & 15) * s + bz;
                wf[2 * dd]     = __builtin_bit_cast(short, __float2bfloat16(w0));
                wf[2 * dd + 1] = __builtin_bit_cast(short, __float2bfloat16(w1));
            }
            acc0 = __builtin_amdgcn_mfma_f32_16x16x32_bf16(a0, wf, acc0, 0, 0, 0);
            acc1 = __builtin_amdgcn_mfma_f32_16x16x32_bf16(a1, wf, acc1, 0, 0, 0);
        }
    }

    __shared__ float red[3][64][9];
    if (kseg != 0) {
#pragma unroll
        for (int e = 0; e < 4; ++e) {
            red[kseg - 1][lane][e]     = acc0[e];
            red[kseg - 1][lane][4 + e] = acc1[e];
        }
    }
    __syncthreads();
    if (kseg == 0) {
#pragma unroll
        for (int ss = 0; ss < 3; ++ss)
#pragma unroll
            for (int e = 0; e < 4; ++e) {
                acc0[e] += red[ss][lane][e];
                acc1[e] += red[ss][lane][4 + e];
            }
        const float bv = bias[n];
#pragma unroll
        for (int r = 0; r < 4; ++r) {
            const int t = kg * 4 + r;
            out[t * NDIM + n]        = acc0[r] + bv;
            out[(t + 16) * NDIM + n] = acc1[r] + bv;
        }
    }
}

extern "C" void kernel_launch(void* const* d_in, const int* in_sizes, int n_in,
                              void* d_out, int out_size, void* d_ws, size_t ws_size,
                              hipStream_t stream) {
    const float* x    = (const float*)d_in[0];
    const int*   qw   = (const int*)d_in[1];
    const float* sc   = (const float*)d_in[2];
    const float* zp   = (const float*)d_in[3];
    const float* bias = (const float*)d_in[4];
    float*       out  = (float*)d_out;

    const size_t part_bytes = (size_t)OUTK * PART_ELEMS * sizeof(float); // ~11.3 MB
    const size_t cnt_bytes  = NBLK_C * sizeof(int);                      // 344 B

    if (ws_size >= part_bytes + cnt_bytes) {
        float* part = (float*)d_ws;
        int*   cnt  = (int*)((char*)d_ws + part_bytes);
        hipMemsetAsync(cnt, 0, cnt_bytes, stream);   // reset finisher counters
        awq_gemm2<<<NBLK_C * OUTK, 512, 0, stream>>>(qw, sc, zp, x, part, cnt,
                                                     bias, out);
    } else {
        awq_gemm_fb<<<NDIM / 16, 256, 0, stream>>>(qw, sc, zp, bias, x, out);
    }
}

// Round 12
// 22.249 us; speedup vs baseline: 10.9974x; 10.9974x over previous
//
#include <hip/hip_runtime.h>
#include <hip/hip_bf16.h>

#define TOKENS 32
#define KDIM   4096
#define NDIM   11008
#define GSZ    64
#define KP     (KDIM/2)          // qweight row length in int32 (2048)
#define NGRP   (KDIM/GSZ)        // 64 groups
#define OUTK   8                 // K-splits across blocks (== 8 XCDs)
#define BLK_COLS 128             // 4 colWaves * 32 cols
#define NBLK_C (NDIM/BLK_COLS)   // 86
#define KSLICE (KDIM/OUTK)       // 512 k per block
#define GPB    (NGRP/OUTK)       // 8 groups per block
#define GPW    (GPB/2)           // 4 groups per wave (2 inner ksegs)
#define QROWS  (BLK_COLS/4)      // 32 qweight rows per block
#define QINTS  (KSLICE/2)        // 256 ints per row slice
#define QSTRIDE 264              // padded (+8 ints = 32B) -> 8-bank shift per row
#define PART_ELEMS (TOKENS*NDIM) // 352256

typedef float  f32x4 __attribute__((ext_vector_type(4)));
typedef int    i32x4 __attribute__((ext_vector_type(4)));
typedef short  s16x8 __attribute__((ext_vector_type(8)));

__device__ __forceinline__ void gload_lds16(const void* g, void* l) {
    __builtin_amdgcn_global_load_lds(
        (const __attribute__((address_space(1))) unsigned int*)g,
        (__attribute__((address_space(3))) unsigned int*)l, 16, 0, 0);
}

// Main GEMM: grid = 688 blocks (86 colGroups x 8 outer-ksegs), 512 thr = 8 waves.
// ob = blockIdx & 7 -> one outer-kseg per XCD (round-robin dispatch).
// K-loop is LDS-ONLY: block stages (a) x K-slice 32KB (f32->bf16 inline, XOR
// swizzle lin^((tok&7)<<4), verified r9/r10) and (b) qweight slice 32 rows x
// 1KB via global_load_lds width=16 (wave-uniform LDS dest = row base, per-lane
// contiguous global src), padded stride so row->bank shift = 8 (<=2-way, free).
// All 16 s/z scalars prefetched to statically-indexed registers upfront.
// Rationale (r11 PMC): VGPR=44 proved reg-prefetch pipelines never materialize;
// LDS staging sidesteps regalloc. Fused-epilogue __threadfence() reverted
// (agent fence = per-XCD L2 writeback/invalidate -> 300us dispatch).
// Dequant EXACT: (float)((q>>sh)&15)*s + (-z*s)  (magic-offset fails absmax).
__global__ __launch_bounds__(512, 2) void awq_gemm2(
    const int* __restrict__ qw, const float* __restrict__ sc,
    const float* __restrict__ zp, const float* __restrict__ xf,
    float* __restrict__ partial) {
    __shared__ unsigned short xs[TOKENS * KSLICE];   // 32768 B (reused for reduce)
    __shared__ int qs[QROWS * QSTRIDE];              // 33792 B

    const int tid  = threadIdx.x;
    const int lane = tid & 63;
    const int wid  = tid >> 6;       // 0..7
    const int cw   = wid & 3;        // colWave
    const int ks   = wid >> 2;       // inner kseg 0..1
    const int ob   = blockIdx.x & 7;         // outer kseg == XCD
    const int bc   = blockIdx.x >> 3;        // col group 0..85
    const int K0   = ob * KSLICE;

    const int col  = lane & 15;
    const int kg   = lane >> 4;                      // k-subgroup 0..3
    const int n0   = bc * BLK_COLS + cw * 32 + col;  // colset-0 column
    const int sh0  = 8 * (n0 & 3);

    // ---- prefetch ALL s/z to registers (issued first, lands during staging) ----
    float s0r[GPW], z0r[GPW], s1r[GPW], z1r[GPW];
#pragma unroll
    for (int gl = 0; gl < GPW; ++gl) {
        const int gg = ob * GPB + ks * GPW + gl;
        s0r[gl] = sc[gg * NDIM + n0];        z0r[gl] = zp[gg * NDIM + n0];
        s1r[gl] = sc[gg * NDIM + n0 + 16];   z1r[gl] = zp[gg * NDIM + n0 + 16];
    }

    // ---- stage x slice: f32 global -> bf16 swizzled LDS ----
#pragma unroll
    for (int it = 0; it < 4; ++it) {
        const int lin  = it * 8192 + tid * 16;       // byte offset in bf16 slice
        const int tok  = lin >> 10;
        const int kloc = (lin & 1023) >> 1;
        const float* xp = xf + tok * KDIM + K0 + kloc;
        f32x4 u0 = *reinterpret_cast<const f32x4*>(xp);
        f32x4 u1 = *reinterpret_cast<const f32x4*>(xp + 4);
        s16x8 v;
#pragma unroll
        for (int e = 0; e < 4; ++e) {
            v[e]     = __builtin_bit_cast(short, __float2bfloat16(u0[e]));
            v[e + 4] = __builtin_bit_cast(short, __float2bfloat16(u1[e]));
        }
        *reinterpret_cast<s16x8*>(
            reinterpret_cast<char*>(xs) + (lin ^ ((tok & 7) << 4))) = v;
    }

    // ---- stage q slice: 32 rows x 1KB, async DMA, wave w -> rows w*4..w*4+3 ----
    const int R0 = bc * QROWS;
#pragma unroll
    for (int i = 0; i < 4; ++i) {
        const int r = wid * 4 + i;
        const int* gsrc = qw + (size_t)(R0 + r) * KP + ob * QINTS + lane * 4;
        gload_lds16(gsrc, &qs[r * QSTRIDE]);
    }
    __syncthreads();   // drains vmcnt (incl. global_load_lds) + lgkm

    f32x4 acc00 = {0,0,0,0}, acc01 = {0,0,0,0};      // [colset][Mtile]
    f32x4 acc10 = {0,0,0,0}, acc11 = {0,0,0,0};

    auto LDSA = [&](int tok, int c) -> s16x8 {       // a-frag from swizzled LDS
        const int inrow = ((c << 6) + (kg << 4)) ^ ((tok & 7) << 4);
        return *reinterpret_cast<const s16x8*>(
            reinterpret_cast<const char*>(xs) + (tok << 10) + inrow);
    };
    auto LDSQ = [&](int lrow, int io) -> i32x4 {
        return *reinterpret_cast<const i32x4*>(&qs[lrow * QSTRIDE + io]);
    };
    auto DQ = [&](const i32x4& q, float s, float bz) -> s16x8 {
        s16x8 wf;
#pragma unroll
        for (int dd = 0; dd < 4; ++dd) {
            const int qd = q[dd];
            float w0 = (float)((qd >> sh0) & 15) * s + bz;        // exact dequant
            float w1 = (float)((qd >> (sh0 + 4)) & 15) * s + bz;
            wf[2 * dd]     = __builtin_bit_cast(short, __float2bfloat16(w0));
            wf[2 * dd + 1] = __builtin_bit_cast(short, __float2bfloat16(w1));
        }
        return wf;
    };

    const int lrow0 = cw * 8 + (col >> 2);           // colset-1 = +4

#pragma unroll
    for (int gl = 0; gl < GPW; ++gl) {
        const int io = (ks * GPW + gl) * 32 + kg * 4;  // int offset in q row
        const int c0 = ks * 8 + gl * 2;                // local K32-chunk
        i32x4 qa0 = LDSQ(lrow0, io),     qa1 = LDSQ(lrow0, io + 16);
        i32x4 qb0 = LDSQ(lrow0 + 4, io), qb1 = LDSQ(lrow0 + 4, io + 16);
        s16x8 a00 = LDSA(col, c0),      a01 = LDSA(col + 16, c0);
        s16x8 a10 = LDSA(col, c0 + 1),  a11 = LDSA(col + 16, c0 + 1);
        const float bz0 = -z0r[gl] * s0r[gl], bz1 = -z1r[gl] * s1r[gl];
        s16x8 w00 = DQ(qa0, s0r[gl], bz0), w01 = DQ(qa1, s0r[gl], bz0);
        s16x8 w10 = DQ(qb0, s1r[gl], bz1), w11 = DQ(qb1, s1r[gl], bz1);
        acc00 = __builtin_amdgcn_mfma_f32_16x16x32_bf16(a00, w00, acc00, 0, 0, 0);
        acc01 = __builtin_amdgcn_mfma_f32_16x16x32_bf16(a01, w00, acc01, 0, 0, 0);
        acc10 = __builtin_amdgcn_mfma_f32_16x16x32_bf16(a00, w10, acc10, 0, 0, 0);
        acc11 = __builtin_amdgcn_mfma_f32_16x16x32_bf16(a01, w10, acc11, 0, 0, 0);
        acc00 = __builtin_amdgcn_mfma_f32_16x16x32_bf16(a10, w01, acc00, 0, 0, 0);
        acc01 = __builtin_amdgcn_mfma_f32_16x16x32_bf16(a11, w01, acc01, 0, 0, 0);
        acc10 = __builtin_amdgcn_mfma_f32_16x16x32_bf16(a10, w11, acc10, 0, 0, 0);
        acc11 = __builtin_amdgcn_mfma_f32_16x16x32_bf16(a11, w11, acc11, 0, 0, 0);
    }

    // ---- inner-kseg reduction through LDS (reuse xs; done reading a-frags) ----
    __syncthreads();
    float (*red)[64][17] = reinterpret_cast<float (*)[64][17]>(xs);  // 17.4KB<32KB
    if (ks == 1) {
#pragma unroll
        for (int e = 0; e < 4; ++e) {
            red[cw][lane][e]      = acc00[e];
            red[cw][lane][4 + e]  = acc01[e];
            red[cw][lane][8 + e]  = acc10[e];
            red[cw][lane][12 + e] = acc11[e];
        }
    }
    __syncthreads();
    if (ks == 0) {
#pragma unroll
        for (int e = 0; e < 4; ++e) {
            acc00[e] += red[cw][lane][e];
            acc01[e] += red[cw][lane][4 + e];
            acc10[e] += red[cw][lane][8 + e];
            acc11[e] += red[cw][lane][12 + e];
        }
        // D layout (verified m89/m91): col = lane&15, row = (lane>>4)*4 + r
        float* pb = partial + (size_t)ob * PART_ELEMS;
#pragma unroll
        for (int r = 0; r < 4; ++r) {
            const int t = kg * 4 + r;
            pb[t * NDIM + n0]             = acc00[r];
            pb[(t + 16) * NDIM + n0]      = acc01[r];
            pb[t * NDIM + n0 + 16]        = acc10[r];
            pb[(t + 16) * NDIM + n0 + 16] = acc11[r];
        }
    }
}

// Epilogue: out = sum(partials) + bias.  88064 f32x4 slots = 688 x 128.
__global__ __launch_bounds__(128) void awq_epi(
    const float* __restrict__ part, const float* __restrict__ bias,
    float* __restrict__ out) {
    const int i = blockIdx.x * 128 + threadIdx.x;    // f32x4 slot, exact fit
    const f32x4* p = reinterpret_cast<const f32x4*>(part);
    f32x4 v = p[i];
#pragma unroll
    for (int o = 1; o < OUTK; ++o) v += p[(size_t)o * (PART_ELEMS / 4) + i];
    v += reinterpret_cast<const f32x4*>(bias)[i % (NDIM / 4)];
    reinterpret_cast<f32x4*>(out)[i] = v;
}

// Fallback (ws too small): round-7 kernel, f32-x path, no ws usage.
__global__ __launch_bounds__(256, 3) void awq_gemm_fb(
    const int* __restrict__ qw, const float* __restrict__ sc,
    const float* __restrict__ zp, const float* __restrict__ bias,
    const float* __restrict__ xf, float* __restrict__ out) {
    const int lane = threadIdx.x & 63;
    const int kseg = threadIdx.x >> 6;
    const int col  = lane & 15;
    const int kg   = lane >> 4;
    const int n    = blockIdx.x * 16 + col;
    const int sh0  = 8 * (n & 3);
    const int* qp  = qw + (n >> 2) * KP + kg * 4;
    const int r0 = col, r1 = col + 16;

    f32x4 acc0 = {0,0,0,0}, acc1 = {0,0,0,0};

    auto cvt8 = [](const float* p) {
        f32x4 u0 = *reinterpret_cast<const f32x4*>(p);
        f32x4 u1 = *reinterpret_cast<const f32x4*>(p + 4);
        s16x8 o;
#pragma unroll
        for (int e = 0; e < 4; ++e) {
            o[e]     = __builtin_bit_cast(short, __float2bfloat16(u0[e]));
            o[e + 4] = __builtin_bit_cast(short, __float2bfloat16(u1[e]));
        }
        return o;
    };

    const int g_lo = kseg * (NGRP / 4), g_hi = g_lo + (NGRP / 4);
#pragma unroll 2
    for (int g = g_lo; g < g_hi; ++g) {
        const float s = sc[g * NDIM + n];
        const float bz = -zp[g * NDIM + n] * s;
#pragma unroll
        for (int h = 0; h < 2; ++h) {
            const int chunk = 2 * g + h;
            i32x4 q = *reinterpret_cast<const i32x4*>(qp + chunk * 16);
            const float* p0 = xf + r0 * KDIM + chunk * 32 + kg * 8;
            const float* p1 = xf + r1 * KDIM + chunk * 32 + kg * 8;
            s16x8 a0 = cvt8(p0), a1 = cvt8(p1);
            s16x8 wf;
#pragma unroll
            for (int dd = 0; dd < 4; ++dd) {
                const int qd = q[dd];
                float w0 = (float)((qd >> sh0) & 15) * s + bz;
                float w1 = (float)((qd >> (sh0 + 4)) & 15) * s + bz;
                wf[2 * dd]     = __builtin_bit_cast(short, __float2bfloat16(w0));
                wf[2 * dd + 1] = __builtin_bit_cast(short, __float2bfloat16(w1));
            }
            acc0 = __builtin_amdgcn_mfma_f32_16x16x32_bf16(a0, wf, acc0, 0, 0, 0);
            acc1 = __builtin_amdgcn_mfma_f32_16x16x32_bf16(a1, wf, acc1, 0, 0, 0);
        }
    }

    __shared__ float red[3][64][9];
    if (kseg != 0) {
#pragma unroll
        for (int e = 0; e < 4; ++e) {
            red[kseg - 1][lane][e]     = acc0[e];
            red[kseg - 1][lane][4 + e] = acc1[e];
        }
    }
    __syncthreads();
    if (kseg == 0) {
#pragma unroll
        for (int ss = 0; ss < 3; ++ss)
#pragma unroll
            for (int e = 0; e < 4; ++e) {
                acc0[e] += red[ss][lane][e];
                acc1[e] += red[ss][lane][4 + e];
            }
        const float bv = bias[n];
#pragma unroll
        for (int r = 0; r < 4; ++r) {
            const int t = kg * 4 + r;
            out[t * NDIM + n]        = acc0[r] + bv;
            out[(t + 16) * NDIM + n] = acc1[r] + bv;
        }
    }
}

extern "C" void kernel_launch(void* const* d_in, const int* in_sizes, int n_in,
                              void* d_out, int out_size, void* d_ws, size_t ws_size,
                              hipStream_t stream) {
    const float* x    = (const float*)d_in[0];
    const int*   qw   = (const int*)d_in[1];
    const float* sc   = (const float*)d_in[2];
    const float* zp   = (const float*)d_in[3];
    const float* bias = (const float*)d_in[4];
    float*       out  = (float*)d_out;

    const size_t part_bytes = (size_t)OUTK * PART_ELEMS * sizeof(float); // ~11.3 MB

    if (ws_size >= part_bytes) {
        float* part = (float*)d_ws;
        awq_gemm2<<<NBLK_C * OUTK, 512, 0, stream>>>(qw, sc, zp, x, part);
        awq_epi<<<PART_ELEMS / 4 / 128, 128, 0, stream>>>(part, bias, out);
    } else {
        awq_gemm_fb<<<NDIM / 16, 256, 0, stream>>>(qw, sc, zp, bias, x, out);
    }
}

// Round 13
// 20.182 us; speedup vs baseline: 12.1235x; 1.1024x over previous
//
#include <hip/hip_runtime.h>
#include <hip/hip_bf16.h>

#define TOKENS 32
#define KDIM   4096
#define NDIM   11008
#define GSZ    64
#define KP     (KDIM/2)          // qweight row length in int32 (2048)
#define NGRP   (KDIM/GSZ)        // 64 groups
#define OUTK   8                 // K-splits across blocks (== 8 XCDs)
#define BLK_COLS 128             // 4 colWaves * 32 cols
#define NBLK_C (NDIM/BLK_COLS)   // 86
#define KSLICE (KDIM/OUTK)       // 512 k per block
#define GPW    (KSLICE/2/GSZ)    // 4 groups per wave (2 inner ksegs)
#define PART_ELEMS (TOKENS*NDIM) // 352256

typedef float  f32x4 __attribute__((ext_vector_type(4)));
typedef int    i32x4 __attribute__((ext_vector_type(4)));
typedef short  s16x8 __attribute__((ext_vector_type(8)));
typedef _Float16 f16x2 __attribute__((ext_vector_type(2)));
typedef _Float16 f16x8 __attribute__((ext_vector_type(8)));

// Main GEMM: grid = 688 blocks, 512 thr = 8 waves.  (r10 structure, 21.1us.)
// ob = blockIdx & 7 -> one outer-kseg per XCD (round-robin dispatch): x slice,
// sc/zp rows, and partial[ob] all XCD-local; qweight slice 2.8MB fits L2.
// Wave = (colWave cw 0..3: 32 cols via 2 B-frags) x (inner kseg ks 0..1).
// Block stages its x K-slice (32 tok x 512 k) from f32, converting to F16
// inline, into XOR-swizzled LDS (byte lin ^ ((tok&7)<<4)); a-frag reads apply
// the same xor to the full in-row offset.
// DEQUANT (f16 packed, r13): per dword 7 VALU ops:
//   u  = (t&15) | ((t&0xF0)<<12) | 0x64006400   // f16 pair (1024+q), EXACT
//   q2 = pk_add(u, -1024)                        // exact (same exponent)
//   w  = pk_fma(q2, {s,s}, {-z*s,-z*s})          // rel err ~5e-4, no group bias
// (r5 lesson: never fold a large constant into the FMA bias -> ~s/2 group
//  offset fails absmax. Here the -1024 subtract is exact, constants are
//  rounded at their own magnitude.)
// Inner ksegs reduced via LDS (unioned with xs); f32 partials to ws.
__global__ __launch_bounds__(512, 2) void awq_gemm2(
    const int* __restrict__ qw, const float* __restrict__ sc,
    const float* __restrict__ zp, const float* __restrict__ xf,
    float* __restrict__ partial) {
    __shared__ unsigned short xs[TOKENS * KSLICE];   // 32 KB (reused for reduce)

    const int tid  = threadIdx.x;
    const int lane = tid & 63;
    const int wid  = tid >> 6;       // 0..7
    const int cw   = wid & 3;        // colWave
    const int ks   = wid >> 2;       // inner kseg 0..1
    const int ob   = blockIdx.x & 7;         // outer kseg == XCD
    const int bc   = blockIdx.x >> 3;        // col group 0..85
    const int K0   = ob * KSLICE;

    const int col  = lane & 15;
    const int kg   = lane >> 4;                      // k-subgroup 0..3
    const int n0   = bc * BLK_COLS + cw * 32 + col;  // colset-0 column
    const int sh0  = 8 * (n0 & 3);
    const int* qp0 = qw + (n0 >> 2) * KP + kg * 4;   // colset-1 = +4*KP ints

    struct GD { float s0, z0, s1, z1; i32x4 qa0, qa1, qb0, qb1; };

    auto LOADG = [&](GD& d, int gl) {
        gl = gl < GPW ? gl : GPW - 1;                // clamp prefetch overhang
        const int gg = ob * (NGRP / OUTK) + ks * GPW + gl;  // global group
        d.s0 = sc[gg * NDIM + n0];        d.z0 = zp[gg * NDIM + n0];
        d.s1 = sc[gg * NDIM + n0 + 16];   d.z1 = zp[gg * NDIM + n0 + 16];
        const int* q = qp0 + gg * 32;
        d.qa0 = *reinterpret_cast<const i32x4*>(q);
        d.qa1 = *reinterpret_cast<const i32x4*>(q + 16);
        d.qb0 = *reinterpret_cast<const i32x4*>(q + 4 * KP);
        d.qb1 = *reinterpret_cast<const i32x4*>(q + 4 * KP + 16);
    };

    // ---- q-prefetch for groups 0/1 issued BEFORE staging (in flight across it) ----
    GD gA, gB;
    LOADG(gA, 0);
    LOADG(gB, 1);

    // ---- stage x slice: f32 global -> f16 swizzled LDS ----
#pragma unroll
    for (int it = 0; it < 4; ++it) {
        const int lin  = it * 8192 + tid * 16;       // byte offset in f16 slice
        const int tok  = lin >> 10;
        const int kloc = (lin & 1023) >> 1;
        const float* xp = xf + tok * KDIM + K0 + kloc;
        f32x4 u0 = *reinterpret_cast<const f32x4*>(xp);
        f32x4 u1 = *reinterpret_cast<const f32x4*>(xp + 4);
        s16x8 v;
#pragma unroll
        for (int e = 0; e < 4; ++e) {
            v[e]     = __builtin_bit_cast(short, (_Float16)u0[e]);
            v[e + 4] = __builtin_bit_cast(short, (_Float16)u1[e]);
        }
        *reinterpret_cast<s16x8*>(
            reinterpret_cast<char*>(xs) + (lin ^ ((tok & 7) << 4))) = v;
    }
    __syncthreads();

    f32x4 acc00 = {0,0,0,0}, acc01 = {0,0,0,0};      // [colset][Mtile]
    f32x4 acc10 = {0,0,0,0}, acc11 = {0,0,0,0};

    auto LDSA = [&](int tok, int c) -> f16x8 {       // a-frag from swizzled LDS
        const int inrow = ((c << 6) + (kg << 4)) ^ ((tok & 7) << 4);
        return *reinterpret_cast<const f16x8*>(
            reinterpret_cast<const char*>(xs) + (tok << 10) + inrow);
    };

    const f16x2 m1024 = {(_Float16)(-1024.0f), (_Float16)(-1024.0f)};

    auto DQ = [&](const i32x4& q, f16x2 s2, f16x2 c2) -> f16x8 {
        i32x4 wu;
#pragma unroll
        for (int dd = 0; dd < 4; ++dd) {
            const int t = q[dd] >> sh0;
            const unsigned u = (unsigned)((t & 15) | ((t & 0xF0) << 12)) | 0x64006400u;
            f16x2 qv = __builtin_bit_cast(f16x2, u);
            f16x2 q2 = qv + m1024;                   // exact: q as f16 pair
            f16x2 w  = __builtin_elementwise_fma(q2, s2, c2);
            wu[dd] = __builtin_bit_cast(int, w);
        }
        return __builtin_bit_cast(f16x8, wu);
    };

    auto COMPUTE = [&](const GD& d, int gl) {
        const int c0 = ks * 8 + gl * 2;              // local K32-chunk
        f16x8 a00 = LDSA(col, c0),      a01 = LDSA(col + 16, c0);
        f16x8 a10 = LDSA(col, c0 + 1),  a11 = LDSA(col + 16, c0 + 1);
        const _Float16 hs0 = (_Float16)d.s0, hs1 = (_Float16)d.s1;
        const _Float16 hc0 = (_Float16)(-d.z0 * d.s0);
        const _Float16 hc1 = (_Float16)(-d.z1 * d.s1);
        const f16x2 s20 = {hs0, hs0}, c20 = {hc0, hc0};
        const f16x2 s21 = {hs1, hs1}, c21 = {hc1, hc1};
        f16x8 w00 = DQ(d.qa0, s20, c20), w01 = DQ(d.qa1, s20, c20);
        f16x8 w10 = DQ(d.qb0, s21, c21), w11 = DQ(d.qb1, s21, c21);
        acc00 = __builtin_amdgcn_mfma_f32_16x16x32_f16(a00, w00, acc00, 0, 0, 0);
        acc01 = __builtin_amdgcn_mfma_f32_16x16x32_f16(a01, w00, acc01, 0, 0, 0);
        acc10 = __builtin_amdgcn_mfma_f32_16x16x32_f16(a00, w10, acc10, 0, 0, 0);
        acc11 = __builtin_amdgcn_mfma_f32_16x16x32_f16(a01, w10, acc11, 0, 0, 0);
        acc00 = __builtin_amdgcn_mfma_f32_16x16x32_f16(a10, w01, acc00, 0, 0, 0);
        acc01 = __builtin_amdgcn_mfma_f32_16x16x32_f16(a11, w01, acc01, 0, 0, 0);
        acc10 = __builtin_amdgcn_mfma_f32_16x16x32_f16(a10, w11, acc10, 0, 0, 0);
        acc11 = __builtin_amdgcn_mfma_f32_16x16x32_f16(a11, w11, acc11, 0, 0, 0);
    };

#pragma unroll
    for (int gl = 0; gl < GPW; gl += 2) {
        COMPUTE(gA, gl);     LOADG(gA, gl + 2);
        COMPUTE(gB, gl + 1); LOADG(gB, gl + 3);
    }

    // ---- inner-kseg reduction through LDS (reuse xs; done reading a-frags) ----
    __syncthreads();
    float (*red)[64][17] = reinterpret_cast<float (*)[64][17]>(xs);  // 17.4KB<32KB
    if (ks == 1) {
#pragma unroll
        for (int e = 0; e < 4; ++e) {
            red[cw][lane][e]      = acc00[e];
            red[cw][lane][4 + e]  = acc01[e];
            red[cw][lane][8 + e]  = acc10[e];
            red[cw][lane][12 + e] = acc11[e];
        }
    }
    __syncthreads();
    if (ks == 0) {
#pragma unroll
        for (int e = 0; e < 4; ++e) {
            acc00[e] += red[cw][lane][e];
            acc01[e] += red[cw][lane][4 + e];
            acc10[e] += red[cw][lane][8 + e];
            acc11[e] += red[cw][lane][12 + e];
        }
        // D layout (verified m89/m91): col = lane&15, row = (lane>>4)*4 + r
        float* pb = partial + (size_t)ob * PART_ELEMS;
#pragma unroll
        for (int r = 0; r < 4; ++r) {
            const int t = kg * 4 + r;
            pb[t * NDIM + n0]             = acc00[r];
            pb[(t + 16) * NDIM + n0]      = acc01[r];
            pb[t * NDIM + n0 + 16]        = acc10[r];
            pb[(t + 16) * NDIM + n0 + 16] = acc11[r];
        }
    }
}

// Epilogue: out = sum(partials) + bias.  88064 f32x4 slots = 688 x 128.
__global__ __launch_bounds__(128) void awq_epi(
    const float* __restrict__ part, const float* __restrict__ bias,
    float* __restrict__ out) {
    const int i = blockIdx.x * 128 + threadIdx.x;    // f32x4 slot, exact fit
    const f32x4* p = reinterpret_cast<const f32x4*>(part);
    f32x4 v = p[i];
#pragma unroll
    for (int o = 1; o < OUTK; ++o) v += p[(size_t)o * (PART_ELEMS / 4) + i];
    v += reinterpret_cast<const f32x4*>(bias)[i % (NDIM / 4)];
    reinterpret_cast<f32x4*>(out)[i] = v;
}

// Fallback (ws too small): round-7 kernel, bf16 path, no ws usage.
__global__ __launch_bounds__(256, 3) void awq_gemm_fb(
    const int* __restrict__ qw, const float* __restrict__ sc,
    const float* __restrict__ zp, const float* __restrict__ bias,
    const float* __restrict__ xf, float* __restrict__ out) {
    const int lane = threadIdx.x & 63;
    const int kseg = threadIdx.x >> 6;
    const int col  = lane & 15;
    const int kg   = lane >> 4;
    const int n    = blockIdx.x * 16 + col;
    const int sh0  = 8 * (n & 3);
    const int* qp  = qw + (n >> 2) * KP + kg * 4;
    const int r0 = col, r1 = col + 16;

    f32x4 acc0 = {0,0,0,0}, acc1 = {0,0,0,0};

    auto cvt8 = [](const float* p) {
        f32x4 u0 = *reinterpret_cast<const f32x4*>(p);
        f32x4 u1 = *reinterpret_cast<const f32x4*>(p + 4);
        s16x8 o;
#pragma unroll
        for (int e = 0; e < 4; ++e) {
            o[e]     = __builtin_bit_cast(short, __float2bfloat16(u0[e]));
            o[e + 4] = __builtin_bit_cast(short, __float2bfloat16(u1[e]));
        }
        return o;
    };

    const int g_lo = kseg * (NGRP / 4), g_hi = g_lo + (NGRP / 4);
#pragma unroll 2
    for (int g = g_lo; g < g_hi; ++g) {
        const float s = sc[g * NDIM + n];
        const float bz = -zp[g * NDIM + n] * s;
#pragma unroll
        for (int h = 0; h < 2; ++h) {
            const int chunk = 2 * g + h;
            i32x4 q = *reinterpret_cast<const i32x4*>(qp + chunk * 16);
            const float* p0 = xf + r0 * KDIM + chunk * 32 + kg * 8;
            const float* p1 = xf + r1 * KDIM + chunk * 32 + kg * 8;
            s16x8 a0 = cvt8(p0), a1 = cvt8(p1);
            s16x8 wf;
#pragma unroll
            for (int dd = 0; dd < 4; ++dd) {
                const int qd = q[dd];
                float w0 = (float)((qd >> sh0) & 15) * s + bz;
                float w1 = (float)((qd >> (sh0 + 4)) & 15) * s + bz;
                wf[2 * dd]     = __builtin_bit_cast(short, __float2bfloat16(w0));
                wf[2 * dd + 1] = __builtin_bit_cast(short, __float2bfloat16(w1));
            }
            acc0 = __builtin_amdgcn_mfma_f32_16x16x32_bf16(a0, wf, acc0, 0, 0, 0);
            acc1 = __builtin_amdgcn_mfma_f32_16x16x32_bf16(a1, wf, acc1, 0, 0, 0);
        }
    }

    __shared__ float red[3][64][9];
    if (kseg != 0) {
#pragma unroll
        for (int e = 0; e < 4; ++e) {
            red[kseg - 1][lane][e]     = acc0[e];
            red[kseg - 1][lane][4 + e] = acc1[e];
        }
    }
    __syncthreads();
    if (kseg == 0) {
#pragma unroll
        for (int ss = 0; ss < 3; ++ss)
#pragma unroll
            for (int e = 0; e < 4; ++e) {
                acc0[e] += red[ss][lane][e];
                acc1[e] += red[ss][lane][4 + e];
            }
        const float bv = bias[n];
#pragma unroll
        for (int r = 0; r < 4; ++r) {
            const int t = kg * 4 + r;
            out[t * NDIM + n]        = acc0[r] + bv;
            out[(t + 16) * NDIM + n] = acc1[r] + bv;
        }
    }
}

extern "C" void kernel_launch(void* const* d_in, const int* in_sizes, int n_in,
                              void* d_out, int out_size, void* d_ws, size_t ws_size,
                              hipStream_t stream) {
    const float* x    = (const float*)d_in[0];
    const int*   qw   = (const int*)d_in[1];
    const float* sc   = (const float*)d_in[2];
    const float* zp   = (const float*)d_in[3];
    const float* bias = (const float*)d_in[4];
    float*       out  = (float*)d_out;

    const size_t part_bytes = (size_t)OUTK * PART_ELEMS * sizeof(float); // ~11.3 MB

    if (ws_size >= part_bytes) {
        float* part = (float*)d_ws;
        awq_gemm2<<<NBLK_C * OUTK, 512, 0, stream>>>(qw, sc, zp, x, part);
        awq_epi<<<PART_ELEMS / 4 / 128, 128, 0, stream>>>(part, bias, out);
    } else {
        awq_gemm_fb<<<NDIM / 16, 256, 0, stream>>>(qw, sc, zp, bias, x, out);
    }
}